// Round 5
// baseline (103.003 us; speedup 1.0000x reference)
//
#include <hip/hip_runtime.h>
#include <math.h>

// Problem constants (setup_inputs: data (16,256,1024) f32)
#define B_   16
#define V_   256
#define R_   1024
#define HR_  20      // G[1]+T[1] = 4+16
#define HV_  10      // G[0]+T[0] = 2+8
#define KTOP 8       // OS_N - K_ORDER = 32-24
#define CAN  16      // 2*T[0]

// Compare-exchange, descending (a=max, b=min)
__device__ __forceinline__ void ce(float& a, float& b) {
    float mx = fmaxf(a, b);
    float mn = fminf(a, b);
    a = mx; b = mn;
}

// Batcher odd-even mergesort, 8 elems, descending, 19 CE
__device__ __forceinline__ void sort8(float* c) {
    ce(c[0],c[1]); ce(c[2],c[3]); ce(c[4],c[5]); ce(c[6],c[7]);
    ce(c[0],c[2]); ce(c[1],c[3]); ce(c[1],c[2]);
    ce(c[4],c[6]); ce(c[5],c[7]); ce(c[5],c[6]);
    ce(c[0],c[4]); ce(c[2],c[6]); ce(c[2],c[4]);
    ce(c[1],c[5]); ce(c[3],c[7]); ce(c[3],c[5]);
    ce(c[1],c[2]); ce(c[3],c[4]); ce(c[5],c[6]);
}

// a,b sorted descending. m = top-8 multiset of a∪b (bitonic), sorted desc
// by a 12-CE bitonic cleaner.
__device__ __forceinline__ void merge_top8_sorted(const float* a, const float* b, float* m) {
#pragma unroll
    for (int i = 0; i < 8; ++i) m[i] = fmaxf(a[i], b[7 - i]);
    ce(m[0],m[4]); ce(m[1],m[5]); ce(m[2],m[6]); ce(m[3],m[7]);
    ce(m[0],m[2]); ce(m[1],m[3]); ce(m[4],m[6]); ce(m[5],m[7]);
    ce(m[0],m[1]); ce(m[2],m[3]); ce(m[4],m[5]); ce(m[6],m[7]);
}

// Textual unroll: E is a literal 0..3 so every array index is compile-time
// constant (no scratch demotion — rule #20).
#define DO_E(E, RESV) {                                                        \
    float c0[8], c1[8], c2[8], c3[8];                                          \
    _Pragma("unroll")                                                          \
    for (int j = 0; j < 8; ++j) {                                              \
        c0[j] = L[(E) + j];                                                    \
        c1[j] = L[(E) + 8 + j];                                                \
        c2[j] = Rr[(E) + 1 + j];                                               \
        c3[j] = Rr[(E) + 9 + j];                                               \
    }                                                                          \
    sort8(c0); sort8(c1); sort8(c2); sort8(c3);                                \
    float m01[8], m23[8];                                                      \
    merge_top8_sorted(c0, c1, m01);                                            \
    merge_top8_sorted(c2, c3, m23);                                            \
    float mn = fminf(                                                          \
        fminf(fminf(fmaxf(m01[0], m23[7]), fmaxf(m01[1], m23[6])),             \
              fminf(fmaxf(m01[2], m23[5]), fmaxf(m01[3], m23[4]))),            \
        fminf(fminf(fmaxf(m01[4], m23[3]), fmaxf(m01[5], m23[2])),             \
              fminf(fmaxf(m01[6], m23[1]), fmaxf(m01[7], m23[0]))));           \
    RESV = alpha * mn;                                                         \
}

// ---------------- Stage 1: OS-CFAR along R ----------------
// One block per (b,v) row; thread t computes r = 4t..4t+3.
// lds[i] = src[(i-20) mod 1024]; window(r) = lds[r..r+15] U lds[r+25..r+40].
__global__ __launch_bounds__(256) void os_kernel(const float* __restrict__ data,
                                                 float* __restrict__ os,
                                                 float alpha) {
    const int row = blockIdx.x;                         // b*V + v
    const float* __restrict__ src = data + (size_t)row * R_;

    __shared__ float lds[R_ + 2 * HR_ + 4];             // 1064 floats
    for (int i = threadIdx.x; i < R_ + 2 * HR_ + 4; i += 256)
        lds[i] = src[(i - HR_) & (R_ - 1)];             // circular
    __syncthreads();

    const int q = threadIdx.x * 4;
    float L[20], Rr[20];
#pragma unroll
    for (int j = 0; j < 5; ++j)
        *(float4*)&L[4 * j] = *(const float4*)&lds[q + 4 * j];
#pragma unroll
    for (int j = 0; j < 5; ++j)
        *(float4*)&Rr[4 * j] = *(const float4*)&lds[q + 24 + 4 * j];

    float res0, res1, res2, res3;
    DO_E(0, res0); DO_E(1, res1); DO_E(2, res2); DO_E(3, res3);

    float4 o; o.x = res0; o.y = res1; o.z = res2; o.w = res3;
    *(float4*)&os[(size_t)row * R_ + q] = o;
}

// ---------------- Stage 2: CA along V (register sliding sums) ----------------
// Thread computes a 4v x 4r output tile. Rows needed: v0+{-10..0} U {+3..+13}
// (22 rows). All 22 float4 loads independent & coalesced; low/high 8-row
// window sums slide in registers.
__device__ __forceinline__ float4 f4add(float4 a, float4 b) {
    return make_float4(a.x + b.x, a.y + b.y, a.z + b.z, a.w + b.w);
}
__device__ __forceinline__ float4 f4sub(float4 a, float4 b) {
    return make_float4(a.x - b.x, a.y - b.y, a.z - b.z, a.w - b.w);
}

__global__ __launch_bounds__(256) void ca_kernel(const float* __restrict__ os,
                                                 float* __restrict__ out) {
    const int tid  = threadIdx.x;
    const int vq   = tid >> 6;                          // 0..3
    const int rq   = tid & 63;
    const int rblk = blockIdx.x & 3;
    const int vblk = (blockIdx.x >> 2) & 15;
    const int b    = blockIdx.x >> 6;
    const int v0   = vblk * 16 + vq * 4;
    const int r    = rblk * 256 + rq * 4;
    const float* __restrict__ base = os + (size_t)b * V_ * R_;
    float* __restrict__ outb = out + (size_t)b * V_ * R_;

    float4 rowv[22];
#pragma unroll
    for (int d = 0; d <= 10; ++d)                       // offsets -10..0
        rowv[d] = *(const float4*)&base[((v0 + d - 10) & (V_ - 1)) * R_ + r];
#pragma unroll
    for (int d = 0; d <= 10; ++d)                       // offsets +3..+13
        rowv[11 + d] = *(const float4*)&base[((v0 + d + 3) & (V_ - 1)) * R_ + r];

    // k=0 windows: low = offsets -10..-3 (idx 0..7), high = +3..+10 (idx 11..18)
    float4 lo = rowv[0];
#pragma unroll
    for (int j = 1; j < 8; ++j) lo = f4add(lo, rowv[j]);
    float4 hi = rowv[11];
#pragma unroll
    for (int j = 12; j < 19; ++j) hi = f4add(hi, rowv[j]);

#pragma unroll
    for (int k = 0; k < 4; ++k) {
        float4 s = f4add(lo, hi);
        float4 o;
        o.x = s.x * (1.0f / CAN); o.y = s.y * (1.0f / CAN);
        o.z = s.z * (1.0f / CAN); o.w = s.w * (1.0f / CAN);
        *(float4*)&outb[(v0 + k) * R_ + r] = o;         // v0+k <= 255, no wrap
        if (k < 3) {
            lo = f4add(f4sub(lo, rowv[k]),      rowv[k + 8]);   // -10+k -> -2+k
            hi = f4add(f4sub(hi, rowv[k + 11]), rowv[k + 19]);  // +3+k  -> +11+k
        }
    }
}

// ---------------- Host: replicate reference alpha solve (float64) ----------------
static double lf_(double n) {
    n = n + 1.0;
    if (n < 9.0) {
        double f = 1.0;
        for (int i = 2; i <= (int)(n + 0.5); ++i) f *= (double)i;
        return log(f);
    }
    return 0.5 * (log(2.0 * M_PI) - log(n)) +
           n * (log(n + 1.0 / (12.0 * n - 0.1 / n)) - 1.0);
}

static double fun_(double k, double n, double t, double pfa) {
    double s = 0.0;
    for (int i = 0; i < (int)k; ++i) s += log(n - (double)i + t);
    return lf_(n) - lf_(n - k) - s - log(pfa);
}

static double solve_alpha_t_ref(void) {
    const double k = 24.0, n = 32.0, pfa = 1e-5;
    double t_max = 1e32, t_min = 1.0, m_n = 1.0;
    for (int it = 0; it < 10000; ++it) {
        double fmax_ = fun_(k, n, t_max, pfa);
        double fmin_ = fun_(k, n, t_min, pfa);
        m_n = t_max - fmax_ * (t_min - t_max) / (fmin_ - fmax_);
        double fm = fun_(k, n, m_n, pfa);
        if (fm == 0.0 || fabs(t_max - t_min) < 1e-4) return m_n;
        if (fmax_ * fm < 0.0)      t_min = m_n;
        else if (fmin_ * fm < 0.0) t_max = m_n;
        else break;
    }
    return m_n;
}

extern "C" void kernel_launch(void* const* d_in, const int* in_sizes, int n_in,
                              void* d_out, int out_size, void* d_ws, size_t ws_size,
                              hipStream_t stream) {
    const float* data = (const float*)d_in[0];
    float* out = (float*)d_out;
    float* os  = (float*)d_ws;                    // 16*256*1024*4 = 16.78 MB

    const float alpha = (float)sqrt(solve_alpha_t_ref());

    os_kernel<<<B_ * V_, 256, 0, stream>>>(data, os, alpha);

    const int blocks2 = B_ * 16 * 4;              // b x vblk x rblk = 1024
    ca_kernel<<<blocks2, 256, 0, stream>>>(os, out);
}

// Round 6
// 87.698 us; speedup vs baseline: 1.1745x; 1.1745x over previous
//
#include <hip/hip_runtime.h>
#include <math.h>

// Problem constants (setup_inputs: data (16,256,1024) f32)
#define B_   16
#define V_   256
#define R_   1024
#define HR_  20      // G[1]+T[1] = 4+16
#define HV_  10      // G[0]+T[0] = 2+8
#define KTOP 8       // OS_N - K_ORDER = 32-24
#define CAN  16      // 2*T[0]

// Compare-exchange, descending (a=max, b=min)
__device__ __forceinline__ void ce(float& a, float& b) {
    float mx = fmaxf(a, b);
    float mn = fminf(a, b);
    a = mx; b = mn;
}

// Batcher odd-even mergesort, 8 elems, descending, 19 CE
__device__ __forceinline__ void sort8(float* c) {
    ce(c[0],c[1]); ce(c[2],c[3]); ce(c[4],c[5]); ce(c[6],c[7]);
    ce(c[0],c[2]); ce(c[1],c[3]); ce(c[1],c[2]);
    ce(c[4],c[6]); ce(c[5],c[7]); ce(c[5],c[6]);
    ce(c[0],c[4]); ce(c[2],c[6]); ce(c[2],c[4]);
    ce(c[1],c[5]); ce(c[3],c[7]); ce(c[3],c[5]);
    ce(c[1],c[2]); ce(c[3],c[4]); ce(c[5],c[6]);
}

// Optimal 6-sorter, descending, 12 CE (verified on 0-1 vectors)
__device__ __forceinline__ void sort6(float* c) {
    ce(c[0],c[5]); ce(c[1],c[3]); ce(c[2],c[4]);
    ce(c[1],c[2]); ce(c[3],c[4]);
    ce(c[0],c[3]); ce(c[2],c[5]);
    ce(c[0],c[1]); ce(c[2],c[3]); ce(c[4],c[5]);
    ce(c[1],c[2]); ce(c[3],c[4]);
}

// a,b sorted descending. m = sorted top-8 multiset of a∪b:
// bitonic maxes + 12-CE bitonic cleaner.
__device__ __forceinline__ void merge_top8_sorted(const float* a, const float* b, float* m) {
#pragma unroll
    for (int i = 0; i < 8; ++i) m[i] = fmaxf(a[i], b[7 - i]);
    ce(m[0],m[4]); ce(m[1],m[5]); ce(m[2],m[6]); ce(m[3],m[7]);
    ce(m[0],m[2]); ce(m[1],m[3]); ce(m[4],m[6]); ce(m[5],m[7]);
    ce(m[0],m[1]); ce(m[2],m[3]); ce(m[4],m[5]); ce(m[6],m[7]);
}

// Per-element finish: merge 6 private extras against the sorted core top-8 m[].
// f_i = max(m[i], ex[7-i]) (ex padded with -inf at 6,7 -> f0=m0 skippable,
// f1=m[1]); 8th-largest = min(f1..f7).
#define FINISH(e0,e1,e2,e3,e4,e5, RESV) {                                      \
    float ex[6] = {e0, e1, e2, e3, e4, e5};                                    \
    sort6(ex);                                                                 \
    float f2 = fmaxf(m[2], ex[5]);                                             \
    float f3 = fmaxf(m[3], ex[4]);                                             \
    float f4 = fmaxf(m[4], ex[3]);                                             \
    float f5 = fmaxf(m[5], ex[2]);                                             \
    float f6 = fmaxf(m[6], ex[1]);                                             \
    float f7 = fmaxf(m[7], ex[0]);                                             \
    float mn = fminf(fminf(fminf(m[1], f2), fminf(f3, f4)),                    \
                     fminf(fminf(f5, f6), f7));                                \
    RESV = alpha * mn;                                                         \
}

// ---------------- Stage 1: OS-CFAR along R ----------------
// One block per (b,v) row; thread t computes r = 4t..4t+3.
// lds[i] = src[(i-20) mod 1024]; window(r) = lds[r..r+15] U lds[r+25..r+40].
// Shared-core decomposition: the 4 windows of one thread share 26 samples
// (L[3..15] U Rr[4..16]); its sorted top-8 is computed once, then each
// element merges only its 6 private extras.
__global__ __launch_bounds__(256) void os_kernel(const float* __restrict__ data,
                                                 float* __restrict__ os,
                                                 float alpha) {
    const int row = blockIdx.x;                         // b*V + v
    const float* __restrict__ src = data + (size_t)row * R_;

    __shared__ float lds[R_ + 2 * HR_ + 4];             // 1064 floats
    for (int i = threadIdx.x; i < R_ + 2 * HR_ + 4; i += 256)
        lds[i] = src[(i - HR_) & (R_ - 1)];             // circular
    __syncthreads();

    const int q = threadIdx.x * 4;
    float L[20], Rr[20];
#pragma unroll
    for (int j = 0; j < 5; ++j)
        *(float4*)&L[4 * j] = *(const float4*)&lds[q + 4 * j];
#pragma unroll
    for (int j = 0; j < 5; ++j)
        *(float4*)&Rr[4 * j] = *(const float4*)&lds[q + 24 + 4 * j];

    // ---- core: sorted top-8 of the 26 shared samples ----
    float c0[8] = {L[3],L[4],L[5],L[6],L[7],L[8],L[9],L[10]};
    float c1[8] = {L[11],L[12],L[13],L[14],L[15],Rr[4],Rr[5],Rr[6]};
    float c2[8] = {Rr[7],Rr[8],Rr[9],Rr[10],Rr[11],Rr[12],Rr[13],Rr[14]};
    sort8(c0); sort8(c1); sort8(c2);
    float m01[8], m[8];
    merge_top8_sorted(c0, c1, m01);
    merge_top8_sorted(m01, c2, m);
    // tail: merge {Rr[15], Rr[16]} (sorted-2 padded with -inf) into m
    float t0 = Rr[15], t1 = Rr[16];
    ce(t0, t1);
    m[6] = fmaxf(m[6], t1);
    m[7] = fmaxf(m[7], t0);
    // bitonic cleaner (sequence is bitonic) -> m = sorted core top-8
    ce(m[0],m[4]); ce(m[1],m[5]); ce(m[2],m[6]); ce(m[3],m[7]);
    ce(m[0],m[2]); ce(m[1],m[3]); ce(m[4],m[6]); ce(m[5],m[7]);
    ce(m[0],m[1]); ce(m[2],m[3]); ce(m[4],m[5]); ce(m[6],m[7]);

    // ---- per-element extras (window(e) = core + 6 extras) ----
    float res0, res1, res2, res3;
    FINISH(L[0],  L[1],  L[2],  Rr[1],  Rr[2],  Rr[3],  res0);
    FINISH(L[1],  L[2],  L[16], Rr[2],  Rr[3],  Rr[17], res1);
    FINISH(L[2],  L[16], L[17], Rr[3],  Rr[17], Rr[18], res2);
    FINISH(L[16], L[17], L[18], Rr[17], Rr[18], Rr[19], res3);

    float4 o; o.x = res0; o.y = res1; o.z = res2; o.w = res3;
    *(float4*)&os[(size_t)row * R_ + q] = o;
}

// ---------------- Stage 2: CA along V (register sliding sums) ----------------
__device__ __forceinline__ float4 f4add(float4 a, float4 b) {
    return make_float4(a.x + b.x, a.y + b.y, a.z + b.z, a.w + b.w);
}
__device__ __forceinline__ float4 f4sub(float4 a, float4 b) {
    return make_float4(a.x - b.x, a.y - b.y, a.z - b.z, a.w - b.w);
}

// Thread computes a 4v x 4r tile. XCD-chunked bijective swizzle (1024 % 8 == 0)
// clusters all blocks of 2 consecutive b's on one XCD -> os slices L2-resident.
__global__ __launch_bounds__(256) void ca_kernel(const float* __restrict__ os,
                                                 float* __restrict__ out) {
    const int swz  = ((blockIdx.x & 7) << 7) | (blockIdx.x >> 3);
    const int tid  = threadIdx.x;
    const int vq   = tid >> 6;                          // 0..3
    const int rq   = tid & 63;
    const int rblk = swz & 3;
    const int vblk = (swz >> 2) & 15;
    const int b    = swz >> 6;
    const int v0   = vblk * 16 + vq * 4;
    const int r    = rblk * 256 + rq * 4;
    const float* __restrict__ base = os + (size_t)b * V_ * R_;
    float* __restrict__ outb = out + (size_t)b * V_ * R_;

    float4 rowv[22];
#pragma unroll
    for (int d = 0; d <= 10; ++d)                       // offsets -10..0
        rowv[d] = *(const float4*)&base[((v0 + d - 10) & (V_ - 1)) * R_ + r];
#pragma unroll
    for (int d = 0; d <= 10; ++d)                       // offsets +3..+13
        rowv[11 + d] = *(const float4*)&base[((v0 + d + 3) & (V_ - 1)) * R_ + r];

    float4 lo = rowv[0];
#pragma unroll
    for (int j = 1; j < 8; ++j) lo = f4add(lo, rowv[j]);
    float4 hi = rowv[11];
#pragma unroll
    for (int j = 12; j < 19; ++j) hi = f4add(hi, rowv[j]);

#pragma unroll
    for (int k = 0; k < 4; ++k) {
        float4 s = f4add(lo, hi);
        float4 o;
        o.x = s.x * (1.0f / CAN); o.y = s.y * (1.0f / CAN);
        o.z = s.z * (1.0f / CAN); o.w = s.w * (1.0f / CAN);
        *(float4*)&outb[(v0 + k) * R_ + r] = o;
        if (k < 3) {
            lo = f4add(f4sub(lo, rowv[k]),      rowv[k + 8]);
            hi = f4add(f4sub(hi, rowv[k + 11]), rowv[k + 19]);
        }
    }
}

// ---------------- Host: replicate reference alpha solve (float64) ----------------
static double lf_(double n) {
    n = n + 1.0;
    if (n < 9.0) {
        double f = 1.0;
        for (int i = 2; i <= (int)(n + 0.5); ++i) f *= (double)i;
        return log(f);
    }
    return 0.5 * (log(2.0 * M_PI) - log(n)) +
           n * (log(n + 1.0 / (12.0 * n - 0.1 / n)) - 1.0);
}

static double fun_(double k, double n, double t, double pfa) {
    double s = 0.0;
    for (int i = 0; i < (int)k; ++i) s += log(n - (double)i + t);
    return lf_(n) - lf_(n - k) - s - log(pfa);
}

static double solve_alpha_t_ref(void) {
    const double k = 24.0, n = 32.0, pfa = 1e-5;
    double t_max = 1e32, t_min = 1.0, m_n = 1.0;
    for (int it = 0; it < 10000; ++it) {
        double fmax_ = fun_(k, n, t_max, pfa);
        double fmin_ = fun_(k, n, t_min, pfa);
        m_n = t_max - fmax_ * (t_min - t_max) / (fmin_ - fmax_);
        double fm = fun_(k, n, m_n, pfa);
        if (fm == 0.0 || fabs(t_max - t_min) < 1e-4) return m_n;
        if (fmax_ * fm < 0.0)      t_min = m_n;
        else if (fmin_ * fm < 0.0) t_max = m_n;
        else break;
    }
    return m_n;
}

extern "C" void kernel_launch(void* const* d_in, const int* in_sizes, int n_in,
                              void* d_out, int out_size, void* d_ws, size_t ws_size,
                              hipStream_t stream) {
    const float* data = (const float*)d_in[0];
    float* out = (float*)d_out;
    float* os  = (float*)d_ws;                    // 16*256*1024*4 = 16.78 MB

    const float alpha = (float)sqrt(solve_alpha_t_ref());

    os_kernel<<<B_ * V_, 256, 0, stream>>>(data, os, alpha);

    const int blocks2 = B_ * 16 * 4;              // 1024
    ca_kernel<<<blocks2, 256, 0, stream>>>(os, out);
}

// Round 8
// 83.714 us; speedup vs baseline: 1.2304x; 1.0476x over previous
//
#include <hip/hip_runtime.h>
#include <hip/hip_fp16.h>
#include <math.h>

// Problem constants (setup_inputs: data (16,256,1024) f32)
#define B_   16
#define V_   256
#define R_   1024
#define HR_  20      // G[1]+T[1] = 4+16
#define HV_  10      // G[0]+T[0] = 2+8
#define KTOP 8       // OS_N - K_ORDER = 32-24
#define CAN  16      // 2*T[0]

// ---------- packed-f16 primitives (2 independent selection problems/lane) ----------
__device__ __forceinline__ unsigned pkrtz(float a, float b) {
    unsigned d;
    asm("v_cvt_pkrtz_f16_f32 %0, %1, %2" : "=v"(d) : "v"(a), "v"(b));
    return d;
}
__device__ __forceinline__ unsigned hmax(unsigned a, unsigned b) {
    unsigned d; asm("v_pk_max_f16 %0, %1, %2" : "=v"(d) : "v"(a), "v"(b)); return d;
}
__device__ __forceinline__ unsigned hmin(unsigned a, unsigned b) {
    unsigned d; asm("v_pk_min_f16 %0, %1, %2" : "=v"(d) : "v"(a), "v"(b)); return d;
}
// compare-exchange, descending (a=max, b=min)
__device__ __forceinline__ void ceh(unsigned& a, unsigned& b) {
    unsigned mx, mn;
    asm("v_pk_max_f16 %0, %2, %3\n\t"
        "v_pk_min_f16 %1, %2, %3"
        : "=&v"(mx), "=v"(mn) : "v"(a), "v"(b));
    a = mx; b = mn;
}
__device__ __forceinline__ float lo16(unsigned u) {
    return __half2float(__ushort_as_half((unsigned short)(u & 0xffffu)));
}
__device__ __forceinline__ float hi16(unsigned u) {
    return __half2float(__ushort_as_half((unsigned short)(u >> 16)));
}

// Batcher odd-even mergesort, 8 elems, descending, 19 CE
__device__ __forceinline__ void sort8h(unsigned* c) {
    ceh(c[0],c[1]); ceh(c[2],c[3]); ceh(c[4],c[5]); ceh(c[6],c[7]);
    ceh(c[0],c[2]); ceh(c[1],c[3]); ceh(c[1],c[2]);
    ceh(c[4],c[6]); ceh(c[5],c[7]); ceh(c[5],c[6]);
    ceh(c[0],c[4]); ceh(c[2],c[6]); ceh(c[2],c[4]);
    ceh(c[1],c[5]); ceh(c[3],c[7]); ceh(c[3],c[5]);
    ceh(c[1],c[2]); ceh(c[3],c[4]); ceh(c[5],c[6]);
}
// Optimal 6-sorter, descending, 12 CE
__device__ __forceinline__ void sort6h(unsigned* c) {
    ceh(c[0],c[5]); ceh(c[1],c[3]); ceh(c[2],c[4]);
    ceh(c[1],c[2]); ceh(c[3],c[4]);
    ceh(c[0],c[3]); ceh(c[2],c[5]);
    ceh(c[0],c[1]); ceh(c[2],c[3]); ceh(c[4],c[5]);
    ceh(c[1],c[2]); ceh(c[3],c[4]);
}
// a,b sorted desc -> m = sorted top-8 multiset of a∪b (bitonic + 12-CE cleaner)
__device__ __forceinline__ void mt8h(const unsigned* a, const unsigned* b, unsigned* m) {
#pragma unroll
    for (int i = 0; i < 8; ++i) m[i] = hmax(a[i], b[7 - i]);
    ceh(m[0],m[4]); ceh(m[1],m[5]); ceh(m[2],m[6]); ceh(m[3],m[7]);
    ceh(m[0],m[2]); ceh(m[1],m[3]); ceh(m[4],m[6]); ceh(m[5],m[7]);
    ceh(m[0],m[1]); ceh(m[2],m[3]); ceh(m[4],m[5]); ceh(m[6],m[7]);
}

// Per-element finish vs sorted core top-8 m[] (extras padded with -inf at 6,7)
#define FINISHH(e0,e1,e2,e3,e4,e5, RES) {                                      \
    unsigned ex[6] = {e0, e1, e2, e3, e4, e5};                                 \
    sort6h(ex);                                                                \
    unsigned f2 = hmax(m[2], ex[5]);                                           \
    unsigned f3 = hmax(m[3], ex[4]);                                           \
    unsigned f4 = hmax(m[4], ex[3]);                                           \
    unsigned f5 = hmax(m[5], ex[2]);                                           \
    unsigned f6 = hmax(m[6], ex[1]);                                           \
    unsigned f7 = hmax(m[7], ex[0]);                                           \
    RES = hmin(hmin(hmin(m[1], f2), hmin(f3, f4)),                             \
               hmin(hmin(f5, f6), f7));                                        \
}

#define ROWSTRIDE 1072   // floats per LDS row (1064 used, padded to x16B)

// ---------------- Stage 1: OS-CFAR along R (packed f16 selection) ----------------
// Block = 2 rows; thread handles 8 consecutive r as two 4-groups packed lo/hi.
// lds[i] = src[(i-20) mod 1024]; x[k] = lds[r0+k] = x_row[r0-20+k], k=0..47.
// Group A (r0..r0+3): L_A[k]=x[k], Rr_A[j]=x[24+j]; group B = shifted by 4.
// Packed: PL[k]=(x[k],x[k+4]), PR[j]=(x[24+j],x[28+j]).
__global__ __launch_bounds__(256) void os_kernel(const float* __restrict__ data,
                                                 float* __restrict__ os,
                                                 float alpha) {
    const int t = threadIdx.x;
    const int row0 = blockIdx.x * 2;
    __shared__ float lds[2 * ROWSTRIDE];

    // Vectorized staging: every 16B block of lds is a contiguous aligned f4
    // of src ((4*bi-20)&1023 is 4-aligned; no mid-block wrap).
    for (int i = t; i < 2 * 266; i += 256) {
        const int rs = (i >= 266) ? 1 : 0;
        const int bi = i - 266 * rs;
        const float* __restrict__ src = data + (size_t)(row0 + rs) * R_;
        const int sf = (4 * bi - HR_) & (R_ - 1);
        *(float4*)&lds[rs * ROWSTRIDE + 4 * bi] = *(const float4*)&src[sf];
    }
    __syncthreads();

    const int rs  = t >> 7;
    const int tid = t & 127;
    const int r0  = tid * 8;
    const float* __restrict__ lr = &lds[rs * ROWSTRIDE];

    float x[48];
#pragma unroll
    for (int j = 0; j < 12; ++j)
        *(float4*)&x[4 * j] = *(const float4*)&lr[r0 + 4 * j];

    unsigned PL[20], PR[20];
#pragma unroll
    for (int k = 0; k < 20; ++k) PL[k] = pkrtz(x[k], x[k + 4]);
#pragma unroll
    for (int k = 0; k < 20; ++k) PR[k] = pkrtz(x[24 + k], x[28 + k]);

    // ---- core: sorted top-8 of the 26 shared samples (both groups packed) ----
    unsigned c0[8] = {PL[3],PL[4],PL[5],PL[6],PL[7],PL[8],PL[9],PL[10]};
    unsigned c1[8] = {PL[11],PL[12],PL[13],PL[14],PL[15],PR[4],PR[5],PR[6]};
    unsigned c2[8] = {PR[7],PR[8],PR[9],PR[10],PR[11],PR[12],PR[13],PR[14]};
    sort8h(c0); sort8h(c1); sort8h(c2);
    unsigned m01[8], m[8];
    mt8h(c0, c1, m01);
    mt8h(m01, c2, m);
    unsigned t0 = PR[15], t1 = PR[16];
    ceh(t0, t1);
    m[6] = hmax(m[6], t1);
    m[7] = hmax(m[7], t0);
    ceh(m[0],m[4]); ceh(m[1],m[5]); ceh(m[2],m[6]); ceh(m[3],m[7]);
    ceh(m[0],m[2]); ceh(m[1],m[3]); ceh(m[4],m[6]); ceh(m[5],m[7]);
    ceh(m[0],m[1]); ceh(m[2],m[3]); ceh(m[4],m[5]); ceh(m[6],m[7]);

    // ---- per-element extras (6 private per element, both groups packed) ----
    unsigned res0, res1, res2, res3;
    FINISHH(PL[0],  PL[1],  PL[2],  PR[1],  PR[2],  PR[3],  res0);
    FINISHH(PL[1],  PL[2],  PL[16], PR[2],  PR[3],  PR[17], res1);
    FINISHH(PL[2],  PL[16], PL[17], PR[3],  PR[17], PR[18], res2);
    FINISHH(PL[16], PL[17], PL[18], PR[17], PR[18], PR[19], res3);

    float4 oA, oB;
    oA.x = alpha * lo16(res0); oB.x = alpha * hi16(res0);
    oA.y = alpha * lo16(res1); oB.y = alpha * hi16(res1);
    oA.z = alpha * lo16(res2); oB.z = alpha * hi16(res2);
    oA.w = alpha * lo16(res3); oB.w = alpha * hi16(res3);
    float* __restrict__ orow = os + (size_t)(row0 + rs) * R_ + r0;
    *(float4*)&orow[0] = oA;
    *(float4*)&orow[4] = oB;
}

// ---------------- Stage 2: CA along V (register sliding sums) ----------------
__device__ __forceinline__ float4 f4add(float4 a, float4 b) {
    return make_float4(a.x + b.x, a.y + b.y, a.z + b.z, a.w + b.w);
}
__device__ __forceinline__ float4 f4sub(float4 a, float4 b) {
    return make_float4(a.x - b.x, a.y - b.y, a.z - b.z, a.w - b.w);
}

__global__ __launch_bounds__(256) void ca_kernel(const float* __restrict__ os,
                                                 float* __restrict__ out) {
    const int swz  = ((blockIdx.x & 7) << 7) | (blockIdx.x >> 3);
    const int tid  = threadIdx.x;
    const int vq   = tid >> 6;
    const int rq   = tid & 63;
    const int rblk = swz & 3;
    const int vblk = (swz >> 2) & 15;
    const int b    = swz >> 6;
    const int v0   = vblk * 16 + vq * 4;
    const int r    = rblk * 256 + rq * 4;
    const float* __restrict__ base = os + (size_t)b * V_ * R_;
    float* __restrict__ outb = out + (size_t)b * V_ * R_;

    float4 rowv[22];
#pragma unroll
    for (int d = 0; d <= 10; ++d)
        rowv[d] = *(const float4*)&base[((v0 + d - 10) & (V_ - 1)) * R_ + r];
#pragma unroll
    for (int d = 0; d <= 10; ++d)
        rowv[11 + d] = *(const float4*)&base[((v0 + d + 3) & (V_ - 1)) * R_ + r];

    float4 lo = rowv[0];
#pragma unroll
    for (int j = 1; j < 8; ++j) lo = f4add(lo, rowv[j]);
    float4 hi = rowv[11];
#pragma unroll
    for (int j = 12; j < 19; ++j) hi = f4add(hi, rowv[j]);

#pragma unroll
    for (int k = 0; k < 4; ++k) {
        float4 s = f4add(lo, hi);
        float4 o;
        o.x = s.x * (1.0f / CAN); o.y = s.y * (1.0f / CAN);
        o.z = s.z * (1.0f / CAN); o.w = s.w * (1.0f / CAN);
        *(float4*)&outb[(v0 + k) * R_ + r] = o;
        if (k < 3) {
            lo = f4add(f4sub(lo, rowv[k]),      rowv[k + 8]);
            hi = f4add(f4sub(hi, rowv[k + 11]), rowv[k + 19]);
        }
    }
}

// ---------------- Host: replicate reference alpha solve (float64) ----------------
static double lf_(double n) {
    n = n + 1.0;
    if (n < 9.0) {
        double f = 1.0;
        for (int i = 2; i <= (int)(n + 0.5); ++i) f *= (double)i;
        return log(f);
    }
    return 0.5 * (log(2.0 * M_PI) - log(n)) +
           n * (log(n + 1.0 / (12.0 * n - 0.1 / n)) - 1.0);
}

static double fun_(double k, double n, double t, double pfa) {
    double s = 0.0;
    for (int i = 0; i < (int)k; ++i) s += log(n - (double)i + t);
    return lf_(n) - lf_(n - k) - s - log(pfa);
}

static double solve_alpha_t_ref(void) {
    const double k = 24.0, n = 32.0, pfa = 1e-5;
    double t_max = 1e32, t_min = 1.0, m_n = 1.0;
    for (int it = 0; it < 10000; ++it) {
        double fmax_ = fun_(k, n, t_max, pfa);
        double fmin_ = fun_(k, n, t_min, pfa);
        m_n = t_max - fmax_ * (t_min - t_max) / (fmin_ - fmax_);
        double fm = fun_(k, n, m_n, pfa);
        if (fm == 0.0 || fabs(t_max - t_min) < 1e-4) return m_n;
        if (fmax_ * fm < 0.0)      t_min = m_n;
        else if (fmin_ * fm < 0.0) t_max = m_n;
        else break;
    }
    return m_n;
}

extern "C" void kernel_launch(void* const* d_in, const int* in_sizes, int n_in,
                              void* d_out, int out_size, void* d_ws, size_t ws_size,
                              hipStream_t stream) {
    const float* data = (const float*)d_in[0];
    float* out = (float*)d_out;
    float* os  = (float*)d_ws;                    // 16*256*1024*4 = 16.78 MB

    const float alpha = (float)sqrt(solve_alpha_t_ref());

    os_kernel<<<B_ * V_ / 2, 256, 0, stream>>>(data, os, alpha);

    const int blocks2 = B_ * 16 * 4;              // 1024
    ca_kernel<<<blocks2, 256, 0, stream>>>(os, out);
}

// Round 9
// 83.455 us; speedup vs baseline: 1.2342x; 1.0031x over previous
//
#include <hip/hip_runtime.h>
#include <hip/hip_fp16.h>
#include <math.h>

// Problem constants (setup_inputs: data (16,256,1024) f32)
#define B_   16
#define V_   256
#define R_   1024
#define HR_  20      // G[1]+T[1] = 4+16
#define HV_  10      // G[0]+T[0] = 2+8
#define KTOP 8       // OS_N - K_ORDER = 32-24
#define CAN  16      // 2*T[0]

// ---------- packed-f16 primitives (2 independent selection problems/lane) ----------
__device__ __forceinline__ unsigned pkrtz(float a, float b) {
    unsigned d;
    asm("v_cvt_pkrtz_f16_f32 %0, %1, %2" : "=v"(d) : "v"(a), "v"(b));
    return d;
}
__device__ __forceinline__ unsigned hmax(unsigned a, unsigned b) {
    unsigned d; asm("v_pk_max_f16 %0, %1, %2" : "=v"(d) : "v"(a), "v"(b)); return d;
}
__device__ __forceinline__ unsigned hmin(unsigned a, unsigned b) {
    unsigned d; asm("v_pk_min_f16 %0, %1, %2" : "=v"(d) : "v"(a), "v"(b)); return d;
}
// compare-exchange, descending (a=max, b=min)
__device__ __forceinline__ void ceh(unsigned& a, unsigned& b) {
    unsigned mx, mn;
    asm("v_pk_max_f16 %0, %2, %3\n\t"
        "v_pk_min_f16 %1, %2, %3"
        : "=&v"(mx), "=v"(mn) : "v"(a), "v"(b));
    a = mx; b = mn;
}
__device__ __forceinline__ float lo16(unsigned u) {
    return __half2float(__ushort_as_half((unsigned short)(u & 0xffffu)));
}
__device__ __forceinline__ float hi16(unsigned u) {
    return __half2float(__ushort_as_half((unsigned short)(u >> 16)));
}

// Batcher odd-even mergesort, 8 elems, descending, 19 CE
__device__ __forceinline__ void sort8h(unsigned* c) {
    ceh(c[0],c[1]); ceh(c[2],c[3]); ceh(c[4],c[5]); ceh(c[6],c[7]);
    ceh(c[0],c[2]); ceh(c[1],c[3]); ceh(c[1],c[2]);
    ceh(c[4],c[6]); ceh(c[5],c[7]); ceh(c[5],c[6]);
    ceh(c[0],c[4]); ceh(c[2],c[6]); ceh(c[2],c[4]);
    ceh(c[1],c[5]); ceh(c[3],c[7]); ceh(c[3],c[5]);
    ceh(c[1],c[2]); ceh(c[3],c[4]); ceh(c[5],c[6]);
}
// Optimal 6-sorter, descending, 12 CE
__device__ __forceinline__ void sort6h(unsigned* c) {
    ceh(c[0],c[5]); ceh(c[1],c[3]); ceh(c[2],c[4]);
    ceh(c[1],c[2]); ceh(c[3],c[4]);
    ceh(c[0],c[3]); ceh(c[2],c[5]);
    ceh(c[0],c[1]); ceh(c[2],c[3]); ceh(c[4],c[5]);
    ceh(c[1],c[2]); ceh(c[3],c[4]);
}
// a,b sorted desc -> m = sorted top-8 multiset of a∪b (bitonic + 12-CE cleaner)
__device__ __forceinline__ void mt8h(const unsigned* a, const unsigned* b, unsigned* m) {
#pragma unroll
    for (int i = 0; i < 8; ++i) m[i] = hmax(a[i], b[7 - i]);
    ceh(m[0],m[4]); ceh(m[1],m[5]); ceh(m[2],m[6]); ceh(m[3],m[7]);
    ceh(m[0],m[2]); ceh(m[1],m[3]); ceh(m[4],m[6]); ceh(m[5],m[7]);
    ceh(m[0],m[1]); ceh(m[2],m[3]); ceh(m[4],m[5]); ceh(m[6],m[7]);
}

// Per-element finish vs sorted core top-8 m[] (extras padded with -inf at 6,7)
#define FINISHH(e0,e1,e2,e3,e4,e5, RES) {                                      \
    unsigned ex[6] = {e0, e1, e2, e3, e4, e5};                                 \
    sort6h(ex);                                                                \
    unsigned f2 = hmax(m[2], ex[5]);                                           \
    unsigned f3 = hmax(m[3], ex[4]);                                           \
    unsigned f4 = hmax(m[4], ex[3]);                                           \
    unsigned f5 = hmax(m[5], ex[2]);                                           \
    unsigned f6 = hmax(m[6], ex[1]);                                           \
    unsigned f7 = hmax(m[7], ex[0]);                                           \
    RES = hmin(hmin(hmin(m[1], f2), hmin(f3, f4)),                             \
               hmin(hmin(f5, f6), f7));                                        \
}

#define ROWSTRIDE 1072   // floats per LDS row (1064 used, 268 16B-blocks)

// XOR-swizzle at 16B-block granularity: b' = b ^ ((b>>3)&7). Involution.
// Kills the 16-way bank-group conflict of 32B-lane-stride ds_read_b128
// (b = 2*tid + j takes only 4 of 8 bank-groups; b' covers all 8 per 8 lanes).
__device__ __forceinline__ int swz(int fi) {
    int b = fi >> 2;
    b ^= (b >> 3) & 7;
    return (b << 2) | (fi & 3);
}

// ---------------- Stage 1: OS-CFAR along R (packed f16 selection) ----------------
// Block = 2 rows; thread handles 8 consecutive r as two 4-groups packed lo/hi.
// lds[i] = src[(i-20) mod 1024]; x[k] = lds[r0+k] = x_row[r0-20+k], k=0..47.
// Packed: PL[k]=(x[k],x[k+4]), PR[j]=(x[24+j],x[28+j]).
__global__ __launch_bounds__(256) void os_kernel(const float* __restrict__ data,
                                                 float* __restrict__ os,
                                                 float alpha) {
    const int t = threadIdx.x;
    const int row0 = blockIdx.x * 2;
    __shared__ float lds[2 * ROWSTRIDE];

    // Vectorized staging: every 16B block of lds is a contiguous aligned f4
    // of src ((4*bi-20)&1023 is 4-aligned; no mid-block wrap). Swizzled dest.
    for (int i = t; i < 2 * 266; i += 256) {
        const int rs = (i >= 266) ? 1 : 0;
        const int bi = i - 266 * rs;
        const float* __restrict__ src = data + (size_t)(row0 + rs) * R_;
        const int sf = (4 * bi - HR_) & (R_ - 1);
        *(float4*)&lds[swz(rs * ROWSTRIDE + 4 * bi)] = *(const float4*)&src[sf];
    }
    __syncthreads();

    const int rs  = t >> 7;
    const int tid = t & 127;
    const int r0  = tid * 8;
    const int lbase = rs * ROWSTRIDE + r0;

    float x[48];
#pragma unroll
    for (int j = 0; j < 12; ++j)
        *(float4*)&x[4 * j] = *(const float4*)&lds[swz(lbase + 4 * j)];

    unsigned PL[20], PR[20];
#pragma unroll
    for (int k = 0; k < 20; ++k) PL[k] = pkrtz(x[k], x[k + 4]);
#pragma unroll
    for (int k = 0; k < 20; ++k) PR[k] = pkrtz(x[24 + k], x[28 + k]);

    // ---- core: sorted top-8 of the 26 shared samples (both groups packed) ----
    unsigned c0[8] = {PL[3],PL[4],PL[5],PL[6],PL[7],PL[8],PL[9],PL[10]};
    unsigned c1[8] = {PL[11],PL[12],PL[13],PL[14],PL[15],PR[4],PR[5],PR[6]};
    unsigned c2[8] = {PR[7],PR[8],PR[9],PR[10],PR[11],PR[12],PR[13],PR[14]};
    sort8h(c0); sort8h(c1); sort8h(c2);
    unsigned m01[8], m[8];
    mt8h(c0, c1, m01);
    mt8h(m01, c2, m);
    unsigned t0 = PR[15], t1 = PR[16];
    ceh(t0, t1);
    m[6] = hmax(m[6], t1);
    m[7] = hmax(m[7], t0);
    ceh(m[0],m[4]); ceh(m[1],m[5]); ceh(m[2],m[6]); ceh(m[3],m[7]);
    ceh(m[0],m[2]); ceh(m[1],m[3]); ceh(m[4],m[6]); ceh(m[5],m[7]);
    ceh(m[0],m[1]); ceh(m[2],m[3]); ceh(m[4],m[5]); ceh(m[6],m[7]);

    // ---- per-element extras (6 private per element, both groups packed) ----
    unsigned res0, res1, res2, res3;
    FINISHH(PL[0],  PL[1],  PL[2],  PR[1],  PR[2],  PR[3],  res0);
    FINISHH(PL[1],  PL[2],  PL[16], PR[2],  PR[3],  PR[17], res1);
    FINISHH(PL[2],  PL[16], PL[17], PR[3],  PR[17], PR[18], res2);
    FINISHH(PL[16], PL[17], PL[18], PR[17], PR[18], PR[19], res3);

    float4 oA, oB;
    oA.x = alpha * lo16(res0); oB.x = alpha * hi16(res0);
    oA.y = alpha * lo16(res1); oB.y = alpha * hi16(res1);
    oA.z = alpha * lo16(res2); oB.z = alpha * hi16(res2);
    oA.w = alpha * lo16(res3); oB.w = alpha * hi16(res3);
    float* __restrict__ orow = os + (size_t)(row0 + rs) * R_ + r0;
    *(float4*)&orow[0] = oA;
    *(float4*)&orow[4] = oB;
}

// ---------------- Stage 2: CA along V (register sliding sums) ----------------
__device__ __forceinline__ float4 f4add(float4 a, float4 b) {
    return make_float4(a.x + b.x, a.y + b.y, a.z + b.z, a.w + b.w);
}
__device__ __forceinline__ float4 f4sub(float4 a, float4 b) {
    return make_float4(a.x - b.x, a.y - b.y, a.z - b.z, a.w - b.w);
}

__global__ __launch_bounds__(256) void ca_kernel(const float* __restrict__ os,
                                                 float* __restrict__ out) {
    const int swzb = ((blockIdx.x & 7) << 7) | (blockIdx.x >> 3);
    const int tid  = threadIdx.x;
    const int vq   = tid >> 6;
    const int rq   = tid & 63;
    const int rblk = swzb & 3;
    const int vblk = (swzb >> 2) & 15;
    const int b    = swzb >> 6;
    const int v0   = vblk * 16 + vq * 4;
    const int r    = rblk * 256 + rq * 4;
    const float* __restrict__ base = os + (size_t)b * V_ * R_;
    float* __restrict__ outb = out + (size_t)b * V_ * R_;

    float4 rowv[22];
#pragma unroll
    for (int d = 0; d <= 10; ++d)
        rowv[d] = *(const float4*)&base[((v0 + d - 10) & (V_ - 1)) * R_ + r];
#pragma unroll
    for (int d = 0; d <= 10; ++d)
        rowv[11 + d] = *(const float4*)&base[((v0 + d + 3) & (V_ - 1)) * R_ + r];

    float4 lo = rowv[0];
#pragma unroll
    for (int j = 1; j < 8; ++j) lo = f4add(lo, rowv[j]);
    float4 hi = rowv[11];
#pragma unroll
    for (int j = 12; j < 19; ++j) hi = f4add(hi, rowv[j]);

#pragma unroll
    for (int k = 0; k < 4; ++k) {
        float4 s = f4add(lo, hi);
        float4 o;
        o.x = s.x * (1.0f / CAN); o.y = s.y * (1.0f / CAN);
        o.z = s.z * (1.0f / CAN); o.w = s.w * (1.0f / CAN);
        *(float4*)&outb[(v0 + k) * R_ + r] = o;
        if (k < 3) {
            lo = f4add(f4sub(lo, rowv[k]),      rowv[k + 8]);
            hi = f4add(f4sub(hi, rowv[k + 11]), rowv[k + 19]);
        }
    }
}

// ---------------- Host: replicate reference alpha solve (float64) ----------------
static double lf_(double n) {
    n = n + 1.0;
    if (n < 9.0) {
        double f = 1.0;
        for (int i = 2; i <= (int)(n + 0.5); ++i) f *= (double)i;
        return log(f);
    }
    return 0.5 * (log(2.0 * M_PI) - log(n)) +
           n * (log(n + 1.0 / (12.0 * n - 0.1 / n)) - 1.0);
}

static double fun_(double k, double n, double t, double pfa) {
    double s = 0.0;
    for (int i = 0; i < (int)k; ++i) s += log(n - (double)i + t);
    return lf_(n) - lf_(n - k) - s - log(pfa);
}

static double solve_alpha_t_ref(void) {
    const double k = 24.0, n = 32.0, pfa = 1e-5;
    double t_max = 1e32, t_min = 1.0, m_n = 1.0;
    for (int it = 0; it < 10000; ++it) {
        double fmax_ = fun_(k, n, t_max, pfa);
        double fmin_ = fun_(k, n, t_min, pfa);
        m_n = t_max - fmax_ * (t_min - t_max) / (fmin_ - fmax_);
        double fm = fun_(k, n, m_n, pfa);
        if (fm == 0.0 || fabs(t_max - t_min) < 1e-4) return m_n;
        if (fmax_ * fm < 0.0)      t_min = m_n;
        else if (fmin_ * fm < 0.0) t_max = m_n;
        else break;
    }
    return m_n;
}

extern "C" void kernel_launch(void* const* d_in, const int* in_sizes, int n_in,
                              void* d_out, int out_size, void* d_ws, size_t ws_size,
                              hipStream_t stream) {
    const float* data = (const float*)d_in[0];
    float* out = (float*)d_out;
    float* os  = (float*)d_ws;                    // 16*256*1024*4 = 16.78 MB

    const float alpha = (float)sqrt(solve_alpha_t_ref());

    os_kernel<<<B_ * V_ / 2, 256, 0, stream>>>(data, os, alpha);

    const int blocks2 = B_ * 16 * 4;              // 1024
    ca_kernel<<<blocks2, 256, 0, stream>>>(os, out);
}

// Round 10
// 82.277 us; speedup vs baseline: 1.2519x; 1.0143x over previous
//
#include <hip/hip_runtime.h>
#include <hip/hip_fp16.h>
#include <math.h>

// Problem constants (setup_inputs: data (16,256,1024) f32)
#define B_   16
#define V_   256
#define R_   1024
#define HR_  20      // G[1]+T[1] = 4+16
#define HV_  10      // G[0]+T[0] = 2+8
#define KTOP 8       // OS_N - K_ORDER = 32-24
#define CAN  16      // 2*T[0]

// ---------- packed-f16 primitives (2 independent selection problems/lane) ----------
__device__ __forceinline__ unsigned pkrtz(float a, float b) {
    unsigned d;
    asm("v_cvt_pkrtz_f16_f32 %0, %1, %2" : "=v"(d) : "v"(a), "v"(b));
    return d;
}
__device__ __forceinline__ unsigned hmax(unsigned a, unsigned b) {
    unsigned d; asm("v_pk_max_f16 %0, %1, %2" : "=v"(d) : "v"(a), "v"(b)); return d;
}
__device__ __forceinline__ unsigned hmin(unsigned a, unsigned b) {
    unsigned d; asm("v_pk_min_f16 %0, %1, %2" : "=v"(d) : "v"(a), "v"(b)); return d;
}
// compare-exchange, descending (a=max, b=min)
__device__ __forceinline__ void ceh(unsigned& a, unsigned& b) {
    unsigned mx, mn;
    asm("v_pk_max_f16 %0, %2, %3\n\t"
        "v_pk_min_f16 %1, %2, %3"
        : "=&v"(mx), "=v"(mn) : "v"(a), "v"(b));
    a = mx; b = mn;
}
__device__ __forceinline__ float lo16(unsigned u) {
    return __half2float(__ushort_as_half((unsigned short)(u & 0xffffu)));
}
__device__ __forceinline__ float hi16(unsigned u) {
    return __half2float(__ushort_as_half((unsigned short)(u >> 16)));
}

// Batcher odd-even mergesort, 8 elems, descending, 19 CE
__device__ __forceinline__ void sort8h(unsigned* c) {
    ceh(c[0],c[1]); ceh(c[2],c[3]); ceh(c[4],c[5]); ceh(c[6],c[7]);
    ceh(c[0],c[2]); ceh(c[1],c[3]); ceh(c[1],c[2]);
    ceh(c[4],c[6]); ceh(c[5],c[7]); ceh(c[5],c[6]);
    ceh(c[0],c[4]); ceh(c[2],c[6]); ceh(c[2],c[4]);
    ceh(c[1],c[5]); ceh(c[3],c[7]); ceh(c[3],c[5]);
    ceh(c[1],c[2]); ceh(c[3],c[4]); ceh(c[5],c[6]);
}
// Optimal 6-sorter, descending, 12 CE
__device__ __forceinline__ void sort6h(unsigned* c) {
    ceh(c[0],c[5]); ceh(c[1],c[3]); ceh(c[2],c[4]);
    ceh(c[1],c[2]); ceh(c[3],c[4]);
    ceh(c[0],c[3]); ceh(c[2],c[5]);
    ceh(c[0],c[1]); ceh(c[2],c[3]); ceh(c[4],c[5]);
    ceh(c[1],c[2]); ceh(c[3],c[4]);
}
// a,b sorted desc -> m = sorted top-8 multiset of a∪b (bitonic + 12-CE cleaner)
__device__ __forceinline__ void mt8h(const unsigned* a, const unsigned* b, unsigned* m) {
#pragma unroll
    for (int i = 0; i < 8; ++i) m[i] = hmax(a[i], b[7 - i]);
    ceh(m[0],m[4]); ceh(m[1],m[5]); ceh(m[2],m[6]); ceh(m[3],m[7]);
    ceh(m[0],m[2]); ceh(m[1],m[3]); ceh(m[4],m[6]); ceh(m[5],m[7]);
    ceh(m[0],m[1]); ceh(m[2],m[3]); ceh(m[4],m[5]); ceh(m[6],m[7]);
}

// Per-element finish vs sorted core top-8 m[] (extras padded with -inf at 6,7)
#define FINISHH(e0,e1,e2,e3,e4,e5, RES) {                                      \
    unsigned ex[6] = {e0, e1, e2, e3, e4, e5};                                 \
    sort6h(ex);                                                                \
    unsigned f2 = hmax(m[2], ex[5]);                                           \
    unsigned f3 = hmax(m[3], ex[4]);                                           \
    unsigned f4 = hmax(m[4], ex[3]);                                           \
    unsigned f5 = hmax(m[5], ex[2]);                                           \
    unsigned f6 = hmax(m[6], ex[1]);                                           \
    unsigned f7 = hmax(m[7], ex[0]);                                           \
    RES = hmin(hmin(hmin(m[1], f2), hmin(f3, f4)),                             \
               hmin(hmin(f5, f6), f7));                                        \
}

// ---------------- Stage 1: OS-CFAR along R (packed f16, DIRECT-GLOBAL loads) ----
// Block = 2 rows x 128 threads; thread handles 8 consecutive r as two packed
// 4-groups (lo/hi f16). x[k] = row[(r0-20+k) & 1023], k=0..47, loaded directly
// from global as 12 float4 (4-aligned, wrap never straddles a 16B block since
// offsets are multiples of 4 and R=1024 is too). Working set 8.6KB/block -> L1.
// No LDS, no __syncthreads.
__global__ __launch_bounds__(256) void os_kernel(const float* __restrict__ data,
                                                 float* __restrict__ os,
                                                 float alpha) {
    const int t = threadIdx.x;
    const int row0 = blockIdx.x * 2;
    const int rs  = t >> 7;
    const int tid = t & 127;
    const int r0  = tid * 8;
    const float* __restrict__ src = data + (size_t)(row0 + rs) * R_;

    float x[48];
#pragma unroll
    for (int j = 0; j < 12; ++j) {
        const int idx = (r0 - HR_ + 4 * j) & (R_ - 1);
        *(float4*)&x[4 * j] = *(const float4*)&src[idx];
    }

    unsigned PL[20], PR[20];
#pragma unroll
    for (int k = 0; k < 20; ++k) PL[k] = pkrtz(x[k], x[k + 4]);
#pragma unroll
    for (int k = 0; k < 20; ++k) PR[k] = pkrtz(x[24 + k], x[28 + k]);

    // ---- core: sorted top-8 of the 26 shared samples (both groups packed) ----
    unsigned c0[8] = {PL[3],PL[4],PL[5],PL[6],PL[7],PL[8],PL[9],PL[10]};
    unsigned c1[8] = {PL[11],PL[12],PL[13],PL[14],PL[15],PR[4],PR[5],PR[6]};
    unsigned c2[8] = {PR[7],PR[8],PR[9],PR[10],PR[11],PR[12],PR[13],PR[14]};
    sort8h(c0); sort8h(c1); sort8h(c2);
    unsigned m01[8], m[8];
    mt8h(c0, c1, m01);
    mt8h(m01, c2, m);
    unsigned t0 = PR[15], t1 = PR[16];
    ceh(t0, t1);
    m[6] = hmax(m[6], t1);
    m[7] = hmax(m[7], t0);
    ceh(m[0],m[4]); ceh(m[1],m[5]); ceh(m[2],m[6]); ceh(m[3],m[7]);
    ceh(m[0],m[2]); ceh(m[1],m[3]); ceh(m[4],m[6]); ceh(m[5],m[7]);
    ceh(m[0],m[1]); ceh(m[2],m[3]); ceh(m[4],m[5]); ceh(m[6],m[7]);

    // ---- per-element extras (6 private per element, both groups packed) ----
    unsigned res0, res1, res2, res3;
    FINISHH(PL[0],  PL[1],  PL[2],  PR[1],  PR[2],  PR[3],  res0);
    FINISHH(PL[1],  PL[2],  PL[16], PR[2],  PR[3],  PR[17], res1);
    FINISHH(PL[2],  PL[16], PL[17], PR[3],  PR[17], PR[18], res2);
    FINISHH(PL[16], PL[17], PL[18], PR[17], PR[18], PR[19], res3);

    float4 oA, oB;
    oA.x = alpha * lo16(res0); oB.x = alpha * hi16(res0);
    oA.y = alpha * lo16(res1); oB.y = alpha * hi16(res1);
    oA.z = alpha * lo16(res2); oB.z = alpha * hi16(res2);
    oA.w = alpha * lo16(res3); oB.w = alpha * hi16(res3);
    float* __restrict__ orow = os + (size_t)(row0 + rs) * R_ + r0;
    *(float4*)&orow[0] = oA;
    *(float4*)&orow[4] = oB;
}

// ---------------- Stage 2: CA along V (register sliding sums) — UNCHANGED ------
__device__ __forceinline__ float4 f4add(float4 a, float4 b) {
    return make_float4(a.x + b.x, a.y + b.y, a.z + b.z, a.w + b.w);
}
__device__ __forceinline__ float4 f4sub(float4 a, float4 b) {
    return make_float4(a.x - b.x, a.y - b.y, a.z - b.z, a.w - b.w);
}

__global__ __launch_bounds__(256) void ca_kernel(const float* __restrict__ os,
                                                 float* __restrict__ out) {
    const int swzb = ((blockIdx.x & 7) << 7) | (blockIdx.x >> 3);
    const int tid  = threadIdx.x;
    const int vq   = tid >> 6;
    const int rq   = tid & 63;
    const int rblk = swzb & 3;
    const int vblk = (swzb >> 2) & 15;
    const int b    = swzb >> 6;
    const int v0   = vblk * 16 + vq * 4;
    const int r    = rblk * 256 + rq * 4;
    const float* __restrict__ base = os + (size_t)b * V_ * R_;
    float* __restrict__ outb = out + (size_t)b * V_ * R_;

    float4 rowv[22];
#pragma unroll
    for (int d = 0; d <= 10; ++d)
        rowv[d] = *(const float4*)&base[((v0 + d - 10) & (V_ - 1)) * R_ + r];
#pragma unroll
    for (int d = 0; d <= 10; ++d)
        rowv[11 + d] = *(const float4*)&base[((v0 + d + 3) & (V_ - 1)) * R_ + r];

    float4 lo = rowv[0];
#pragma unroll
    for (int j = 1; j < 8; ++j) lo = f4add(lo, rowv[j]);
    float4 hi = rowv[11];
#pragma unroll
    for (int j = 12; j < 19; ++j) hi = f4add(hi, rowv[j]);

#pragma unroll
    for (int k = 0; k < 4; ++k) {
        float4 s = f4add(lo, hi);
        float4 o;
        o.x = s.x * (1.0f / CAN); o.y = s.y * (1.0f / CAN);
        o.z = s.z * (1.0f / CAN); o.w = s.w * (1.0f / CAN);
        *(float4*)&outb[(v0 + k) * R_ + r] = o;
        if (k < 3) {
            lo = f4add(f4sub(lo, rowv[k]),      rowv[k + 8]);
            hi = f4add(f4sub(hi, rowv[k + 11]), rowv[k + 19]);
        }
    }
}

// ---------------- Host: replicate reference alpha solve (float64) ----------------
static double lf_(double n) {
    n = n + 1.0;
    if (n < 9.0) {
        double f = 1.0;
        for (int i = 2; i <= (int)(n + 0.5); ++i) f *= (double)i;
        return log(f);
    }
    return 0.5 * (log(2.0 * M_PI) - log(n)) +
           n * (log(n + 1.0 / (12.0 * n - 0.1 / n)) - 1.0);
}

static double fun_(double k, double n, double t, double pfa) {
    double s = 0.0;
    for (int i = 0; i < (int)k; ++i) s += log(n - (double)i + t);
    return lf_(n) - lf_(n - k) - s - log(pfa);
}

static double solve_alpha_t_ref(void) {
    const double k = 24.0, n = 32.0, pfa = 1e-5;
    double t_max = 1e32, t_min = 1.0, m_n = 1.0;
    for (int it = 0; it < 10000; ++it) {
        double fmax_ = fun_(k, n, t_max, pfa);
        double fmin_ = fun_(k, n, t_min, pfa);
        m_n = t_max - fmax_ * (t_min - t_max) / (fmin_ - fmax_);
        double fm = fun_(k, n, m_n, pfa);
        if (fm == 0.0 || fabs(t_max - t_min) < 1e-4) return m_n;
        if (fmax_ * fm < 0.0)      t_min = m_n;
        else if (fmin_ * fm < 0.0) t_max = m_n;
        else break;
    }
    return m_n;
}

extern "C" void kernel_launch(void* const* d_in, const int* in_sizes, int n_in,
                              void* d_out, int out_size, void* d_ws, size_t ws_size,
                              hipStream_t stream) {
    const float* data = (const float*)d_in[0];
    float* out = (float*)d_out;
    float* os  = (float*)d_ws;                    // 16*256*1024*4 = 16.78 MB

    const float alpha = (float)sqrt(solve_alpha_t_ref());

    os_kernel<<<B_ * V_ / 2, 256, 0, stream>>>(data, os, alpha);

    const int blocks2 = B_ * 16 * 4;              // 1024
    ca_kernel<<<blocks2, 256, 0, stream>>>(os, out);
}